// Round 8
// baseline (584.112 us; speedup 1.0000x reference)
//
#include <hip/hip_runtime.h>
#include <hip/hip_cooperative_groups.h>

namespace cg = cooperative_groups;

// GCN layer: out = (D^-1/2 (A+I) D^-1/2) X W^T + b
// N=100000, E=1600000, D=64.
//
// Round 8: single cooperative mega-kernel. Round-7 ledger: gather 54us known,
// fused<54, csr<54, yet total 191 -> ~30-50us in dispatch boundaries + two
// under-parallelized build kernels (scatter 1.5 blocks/CU, csr 3/CU), each
// boundary draining the whole machine. Fix: one hipLaunchCooperativeKernel,
// grid-strided phases, grid.sync() between:
//   P0 zero gcur/tileCtr (kills the memset dispatch)
//   P1 scatter chunks (blocks 0..390; LDS cut to 6.3KB by re-reading ei from
//      L1 at write-out) + dynamic gemm tile pool (ALL blocks; scatter
//      imbalance absorbed by gemm work instead of idle CUs)
//   P2 per-bucket csr sort (logic unchanged from round 7)
//   P3 gather, wave-strided nodes; inner loop identical to the proven 54us
//      kernel. Residency ~24 waves/CU ~= round-7's ~22 (round-4 lesson:
//      resident-wave count, not chain length, governs latency-bound gathers).
// Numerics unchanged -> absmax should stay 3.9e-3.

#define BSHIFT 7
#define BNODES 128
#define CAP 3072        // records per bucket region (mean 2046, P(overflow)~1e-90)
#define EPB 4096        // edges per scatter chunk -> 391 chunks
#define GEMM_ROWS 32    // gemm tile rows
#define AT_STRIDE 34    // k-major A-tile stride (even: float2 reads, low conflict)
#define SMEM_BYTES 25088  // max(gemm Wt 16384 + At 64*34*4=8704, scatter 6.3K, csr 13.3K)

__device__ inline unsigned short f2b_rn(float f) {
    unsigned u = __float_as_uint(f);
    unsigned r = u + 0x7FFFu + ((u >> 16) & 1u);
    return (unsigned short)(r >> 16);
}
__device__ inline float b2f(unsigned short h) {
    return __uint_as_float(((unsigned)h) << 16);
}

__global__ __launch_bounds__(256) void mega_kernel(
    const float* __restrict__ x, const float* __restrict__ W,
    const float* __restrict__ bias, const int* __restrict__ ei,
    float* __restrict__ out,
    int* __restrict__ gcur, int* __restrict__ tileCtr,
    unsigned int* __restrict__ grec,
    int* __restrict__ offb, int* __restrict__ offe, float* __restrict__ dis,
    ushort4* __restrict__ yh,
    int n, int e, int nbuck, int nchunks, int ntiles) {
    __shared__ __align__(16) unsigned char smem[SMEM_BYTES];
    __shared__ int cur_tile;
    __shared__ int wtot;
    cg::grid_group grid = cg::this_grid();
    int t = threadIdx.x;
    int bid = blockIdx.x;
    int G = gridDim.x;

    // ---- P0: zero cursors ----
    for (int i = bid * 256 + t; i <= nbuck; i += G * 256) {
        if (i < nbuck) gcur[i] = 0;
        else tileCtr[0] = 0;
    }
    __threadfence();
    grid.sync();

    // ---- P1a: binned scatter (grid-strided chunks) ----
    {
        int* lh = (int*)smem;          // [nbuck] hist, then cursor
        int* lbase = lh + nbuck;       // [nbuck]
        for (int c = bid; c < nchunks; c += G) {
            for (int i = t; i < nbuck; i += 256) lh[i] = 0;
            __syncthreads();
            int e0 = c * EPB;
            int m = e - e0;
            if (m > EPB) m = EPB;
            for (int i = t; i < m; i += 256)
                atomicAdd(&lh[ei[e + e0 + i] >> BSHIFT], 1);
            __syncthreads();
            for (int b = t; b < nbuck; b += 256) {
                int cc = lh[b];
                lbase[b] = cc ? atomicAdd(&gcur[b], cc) : 0;
                lh[b] = 0;  // reuse as local cursor
            }
            __syncthreads();
            for (int i = t; i < m; i += 256) {
                int g = e0 + i;
                int s = ei[g];          // L1-hot (read in hist pass)
                int d = ei[e + g];
                int b = d >> BSHIFT;
                int pos = lbase[b] + atomicAdd(&lh[b], 1);
                if (pos < CAP)
                    grec[(size_t)b * CAP + pos] =
                        ((unsigned int)s << BSHIFT) | (unsigned int)(d & (BNODES - 1));
            }
            __syncthreads();  // before next chunk reuses lh
        }
    }

    // ---- P1b: gemm tile pool (all blocks; y = x @ W^T, bf16 out) ----
    {
        float* Wt = (float*)smem;             // [64*64] Wt[k*64+o] = W[o*64+k]
        float* At = (float*)(smem + 16384);   // [64*AT_STRIDE] k-major
        __syncthreads();  // scatter-phase smem use done (block-local)
#pragma unroll
        for (int j = 0; j < 16; ++j) {
            int idx = t + j * 256;
            int o = idx >> 6, k = idx & 63;
            Wt[k * 64 + o] = W[idx];
        }
        __syncthreads();
        while (true) {
            if (t == 0) cur_tile = atomicAdd(tileCtr, 1);
            __syncthreads();
            int tile = cur_tile;
            if (tile >= ntiles) break;
            int m0 = tile * GEMM_ROWS;
#pragma unroll
            for (int j = 0; j < 8; ++j) {
                int idx = t + j * 256;
                int mm = idx >> 6, k = idx & 63;  // lane-consecutive k -> coalesced
                int gm = m0 + mm;
                At[k * AT_STRIDE + mm] = (gm < n) ? x[(size_t)gm * 64 + k] : 0.f;
            }
            __syncthreads();
            int tx = t & 15, ty = t >> 4;  // tx: out quad; ty: row pair
            float acc[2][4];
#pragma unroll
            for (int i = 0; i < 2; ++i)
#pragma unroll
                for (int j = 0; j < 4; ++j) acc[i][j] = 0.f;
#pragma unroll 8
            for (int k = 0; k < 64; ++k) {
                float2 a = *(const float2*)&At[k * AT_STRIDE + ty * 2];
                float4 w = *(const float4*)&Wt[k * 64 + tx * 4];
                acc[0][0] += a.x * w.x; acc[0][1] += a.x * w.y;
                acc[0][2] += a.x * w.z; acc[0][3] += a.x * w.w;
                acc[1][0] += a.y * w.x; acc[1][1] += a.y * w.y;
                acc[1][2] += a.y * w.z; acc[1][3] += a.y * w.w;
            }
#pragma unroll
            for (int i = 0; i < 2; ++i) {
                int gm = m0 + ty * 2 + i;
                if (gm < n) {
                    ushort4 h;
                    h.x = f2b_rn(acc[i][0]);
                    h.y = f2b_rn(acc[i][1]);
                    h.z = f2b_rn(acc[i][2]);
                    h.w = f2b_rn(acc[i][3]);
                    yh[(size_t)gm * 16 + tx] = h;
                }
            }
            __syncthreads();  // before next At stage / cur_tile overwrite
        }
    }

    __threadfence();
    grid.sync();

    // ---- P2: per-bucket in-place sort -> src ids grouped by dst ----
    {
        unsigned int* recs = (unsigned int*)smem;       // [CAP] 12288 B
        int* clh = (int*)(smem + 12288);                // [BNODES]
        int* cls = (int*)(smem + 12288 + 512);          // [BNODES]
        int lane = t & 63;
        for (int b = bid; b < nbuck; b += G) {
            size_t base = (size_t)b * CAP;
            int cnt = gcur[b];
            if (cnt > CAP) cnt = CAP;
            int node0 = b << BSHIFT;
            if (t < BNODES) clh[t] = 0;
            __syncthreads();
            for (int i = t; i < cnt; i += 256) {
                unsigned int r = grec[base + i];
                recs[i] = r;
                atomicAdd(&clh[r & (BNODES - 1)], 1);
            }
            __syncthreads();
            int c = (t < BNODES) ? clh[t] : 0;
            int v = c;  // inclusive shfl scan over 128 bins (waves 0,1)
#pragma unroll
            for (int o = 1; o < 64; o <<= 1) {
                int u = __shfl_up(v, o, 64);
                if (lane >= o) v += u;
            }
            if (t == 63) wtot = v;
            __syncthreads();
            if (t >= 64 && t < BNODES) v += wtot;
            int ex = v - c;
            if (t < BNODES) {
                int node = node0 + t;
                if (node < n) {
                    offb[node] = (int)base + ex;
                    offe[node] = (int)base + ex + c;
                    dis[node] = rsqrtf((float)(c + 1));  // +1 self loop
                }
                cls[t] = ex;
                clh[t] = 0;  // cursor
            }
            __syncthreads();
            for (int i = t; i < cnt; i += 256) {
                unsigned int r = recs[i];
                int nd = r & (BNODES - 1);
                int pos = cls[nd] + atomicAdd(&clh[nd], 1);
                grec[base + pos] = r >> BSHIFT;  // src id only
            }
            __syncthreads();
        }
    }

    __threadfence();
    grid.sync();

    // ---- P3: gather over bf16 y-rows, wave-strided nodes ----
    {
        int lane = t & 63;
        int grp = lane >> 4;   // which of 4 concurrent edges
        int fq = lane & 15;    // feature quad
        int gw = bid * 4 + (t >> 6);
        for (int node = gw; node < n; node += G * 4) {
            int beg = offb[node];
            int end = offe[node];
            float dn = dis[node];
            float4 acc = {0.f, 0.f, 0.f, 0.f};
            if (grp == 0) {  // self loop
                ushort4 h = yh[(size_t)node * 16 + fq];
                acc.x = b2f(h.x) * dn; acc.y = b2f(h.y) * dn;
                acc.z = b2f(h.z) * dn; acc.w = b2f(h.w) * dn;
            }
            for (int c = beg; c < end; c += 64) {
                int k = end - c;
                if (k > 64) k = 64;
                int sidx = 0;
                float dv = 0.f;
                if (lane < k) {
                    sidx = (int)grec[c + lane];
                    dv = dis[sidx];
                }
                for (int j = 0; j < k; j += 4) {
                    int jj = j + grp;
                    int s = __shfl(sidx, jj);
                    float w = __shfl(dv, jj);   // lanes >= k carry w=0 -> harmless
                    ushort4 h = yh[(size_t)s * 16 + fq];  // 128B row
                    acc.x += b2f(h.x) * w;
                    acc.y += b2f(h.y) * w;
                    acc.z += b2f(h.z) * w;
                    acc.w += b2f(h.w) * w;
                }
            }
            for (int m = 16; m < 64; m <<= 1) {
                acc.x += __shfl_xor(acc.x, m);
                acc.y += __shfl_xor(acc.y, m);
                acc.z += __shfl_xor(acc.z, m);
                acc.w += __shfl_xor(acc.w, m);
            }
            if (lane < 16) {
                float4 bb = ((const float4*)bias)[fq];
                float4 o;
                o.x = acc.x * dn + bb.x;
                o.y = acc.y * dn + bb.y;
                o.z = acc.z * dn + bb.z;
                o.w = acc.w * dn + bb.w;
                ((float4*)out)[(size_t)node * 16 + lane] = o;
            }
        }
    }
}

extern "C" void kernel_launch(void* const* d_in, const int* in_sizes, int n_in,
                              void* d_out, int out_size, void* d_ws, size_t ws_size,
                              hipStream_t stream) {
    const float* x    = (const float*)d_in[0];
    const int*   ei   = (const int*)d_in[1];  // [2,E]: src row then dst row
    const float* W    = (const float*)d_in[2];
    const float* bias = (const float*)d_in[3];
    float* out = (float*)d_out;

    int n = in_sizes[0] / 64;
    int e = in_sizes[1] / 2;
    int nbuck = (n + BNODES - 1) / BNODES;        // 782
    int nchunks = (e + EPB - 1) / EPB;            // 391
    int ntiles = (n + GEMM_ROWS - 1) / GEMM_ROWS; // 3125

    // workspace (256B aligned): gcur | tileCtr | offb | offe | dis | grec | yh (~23.7MB)
    auto align = [](size_t v) { return (v + 255) & ~(size_t)255; };
    char* p = (char*)d_ws;
    int* gcur = (int*)p;          p += align((size_t)nbuck * 4);
    int* tileCtr = (int*)p;       p += align(4);
    int* offb = (int*)p;          p += align((size_t)n * 4);
    int* offe = (int*)p;          p += align((size_t)n * 4);
    float* dis = (float*)p;       p += align((size_t)n * 4);
    unsigned int* grec = (unsigned int*)p;  p += align((size_t)nbuck * CAP * 4);
    ushort4* yh = (ushort4*)p;

    // all-resident grid size from the occupancy API (pure query: capture-safe,
    // deterministic -> same work every call)
    int occ = 0;
    hipOccupancyMaxActiveBlocksPerMultiprocessor(&occ, mega_kernel, 256, 0);
    if (occ < 1) occ = 1;
    if (occ > 8) occ = 8;
    int G = occ * 256;  // MI355X: 256 CUs

    void* args[] = {(void*)&x, (void*)&W, (void*)&bias, (void*)&ei, (void*)&out,
                    (void*)&gcur, (void*)&tileCtr, (void*)&grec,
                    (void*)&offb, (void*)&offe, (void*)&dis, (void*)&yh,
                    (void*)&n, (void*)&e, (void*)&nbuck, (void*)&nchunks, (void*)&ntiles};
    hipLaunchCooperativeKernel(mega_kernel, dim3(G), dim3(256), args, 0, stream);
}

// Round 9
// 242.469 us; speedup vs baseline: 2.4090x; 2.4090x over previous
//
#include <hip/hip_runtime.h>

// GCN layer: out = (D^-1/2 (A+I) D^-1/2) X W^T + b
// N=100000, E=1600000, D=64.
//
// Round 9: revert round-8 megakernel (584us, VALU 3.2% — grid.sync phase
// serialization; lesson: fuse only INDEPENDENT work into one dispatch).
// Back to round-7 skeleton (191us) plus an algebraic restructure:
//   y'_i = dis_i * (x_i W^T)  computed in the GEMM epilogue (needs deg first)
//   out_i = dn_i * (sum_e y'_src + y'_i) + bias
// so the gather needs NO per-edge dis load, NO shfl staging, NO multiply,
// and csr can fuse INTO gather (sort is per-bucket local): one 1024-thread
// block per bucket sorts its records into LDS, derives per-node offsets and
// dn = rsqrt(deg+1) from the local hist (offb/offe/dis arrays deleted), then
// its 16 waves gather 8 nodes each at 32 waves/CU (vs round-7's 24).
//
// Pipeline (4 dispatches, plain launches):
//   D1 memset deg+gcur
//   D2 hist: deg[dst]++  (1.6M int atomics, ~8us)
//   D3 fused: gemm y'=dis*xW^T (bf16) || binned scatter (round-7 internals)
//   D4 csr_gather: per-bucket LDS sort + gather + bias

#define BSHIFT 7
#define BNODES 128
#define CAP 3072   // records per bucket region (mean 2046, P(overflow)~1e-90)
#define EPB 4096   // edges per scatter block -> 391 blocks
#define SMEM_BYTES 33792  // max(gemm 33792, scatter 24576+nbuck*8 with nbuck<=1152)

__device__ inline unsigned short f2b_rn(float f) {
    unsigned u = __float_as_uint(f);
    unsigned r = u + 0x7FFFu + ((u >> 16) & 1u);
    return (unsigned short)(r >> 16);
}
__device__ inline float b2f(unsigned short h) {
    return __uint_as_float(((unsigned)h) << 16);
}

// --- D2: per-node in-degree histogram ---
__global__ __launch_bounds__(256) void hist_kernel(const int* __restrict__ dst,
                                                   int* __restrict__ deg, int e) {
    int i = blockIdx.x * 256 + threadIdx.x;
    if (i < e) atomicAdd(&deg[dst[i]], 1);
}

// --- D3: fused gemm || scatter (independent work, one dispatch) ---
__global__ __launch_bounds__(256) void fused_gemm_scatter_kernel(
    const float* __restrict__ x, const float* __restrict__ W,
    const int* __restrict__ deg, ushort4* __restrict__ yh,
    const int* __restrict__ ei, int* __restrict__ gcur,
    unsigned int* __restrict__ grec,
    int n, int e, int nbuck, int sblocks) {
    __shared__ __align__(16) unsigned char smem[SMEM_BYTES];
    int t = threadIdx.x;

    if ((int)blockIdx.x < sblocks) {
        // ---- binned scatter into fixed-capacity bucket regions (r7-proven) ----
        unsigned int* lrec = (unsigned int*)smem;               // EPB*4 = 16384
        unsigned short* lbk = (unsigned short*)(smem + 16384);  // EPB*2 = 8192
        int* lh = (int*)(smem + 24576);                         // [nbuck]
        int* lbase = lh + nbuck;                                // [nbuck]
        for (int i = t; i < nbuck; i += 256) lh[i] = 0;
        __syncthreads();
        int e0 = blockIdx.x * EPB;
        int m = e - e0;
        if (m > EPB) m = EPB;
        for (int i = t; i < m; i += 256) {
            int g = e0 + i;
            int s = ei[g];
            int d = ei[e + g];
            int b = d >> BSHIFT;
            lrec[i] = ((unsigned int)s << BSHIFT) | (unsigned int)(d & (BNODES - 1));
            lbk[i] = (unsigned short)b;
            atomicAdd(&lh[b], 1);
        }
        __syncthreads();
        for (int b = t; b < nbuck; b += 256) {
            int c = lh[b];
            lbase[b] = c ? atomicAdd(&gcur[b], c) : 0;
            lh[b] = 0;  // reuse as local cursor
        }
        __syncthreads();
        for (int i = t; i < m; i += 256) {
            int b = lbk[i];
            int pos = lbase[b] + atomicAdd(&lh[b], 1);
            if (pos < CAP)
                grec[(size_t)b * CAP + pos] = lrec[i];
        }
    } else {
        // ---- gemm: y' = dis * (x @ W^T), bf16 out ----
        float* At = (float*)smem;            // 64*68*4 = 17408, k-major stride 68
        float* Wt = (float*)(smem + 17408);  // 64*64*4 = 16384
        int m0 = ((int)blockIdx.x - sblocks) * 64;

#pragma unroll
        for (int j = 0; j < 16; ++j) {
            int idx = t + j * 256;
            int o = idx >> 6, k = idx & 63;
            Wt[k * 64 + o] = W[idx];
        }
#pragma unroll
        for (int j = 0; j < 16; ++j) {
            int idx = t + j * 256;
            int mm = idx >> 6, k = idx & 63;
            int gm = m0 + mm;
            At[k * 68 + mm] = (gm < n) ? x[(size_t)gm * 64 + k] : 0.f;
        }
        __syncthreads();

        int tx = t & 15, ty = t >> 4;
        float acc[4][4];
#pragma unroll
        for (int i = 0; i < 4; ++i)
#pragma unroll
            for (int j = 0; j < 4; ++j) acc[i][j] = 0.f;

#pragma unroll 8
        for (int k = 0; k < 64; ++k) {
            float4 a = *(const float4*)&At[k * 68 + ty * 4];
            float4 w = *(const float4*)&Wt[k * 64 + tx * 4];
            float av[4] = {a.x, a.y, a.z, a.w};
            float wv[4] = {w.x, w.y, w.z, w.w};
#pragma unroll
            for (int i = 0; i < 4; ++i)
#pragma unroll
                for (int j = 0; j < 4; ++j) acc[i][j] += av[i] * wv[j];
        }

#pragma unroll
        for (int i = 0; i < 4; ++i) {
            int gm = m0 + ty * 4 + i;
            if (gm < n) {
                float dn = rsqrtf((float)(deg[gm] + 1));  // +1 self loop
                ushort4 h;
                h.x = f2b_rn(acc[i][0] * dn);
                h.y = f2b_rn(acc[i][1] * dn);
                h.z = f2b_rn(acc[i][2] * dn);
                h.w = f2b_rn(acc[i][3] * dn);
                yh[(size_t)gm * 16 + tx] = h;
            }
        }
    }
}

// --- D4: per-bucket fused sort + gather ---
// 1024 threads (16 waves) per bucket: hist -> shfl scan -> sort src ids into
// LDS -> each wave gathers 8 nodes. Offsets, degree, dn all LDS-local.
__global__ __launch_bounds__(1024, 8) void csr_gather_kernel(
    const unsigned int* __restrict__ grec, const int* __restrict__ gcur,
    const ushort4* __restrict__ yh, const float* __restrict__ bias,
    float4* __restrict__ out, int n) {
    __shared__ unsigned int sorted[CAP];  // 12288 B: src ids grouped by dst
    __shared__ int lh[BNODES];            // hist, then cursor
    __shared__ int ls[BNODES + 1];        // exclusive offsets; ls[128] = cnt
    __shared__ int wtot;
    int t = threadIdx.x;
    int b = blockIdx.x;
    size_t base = (size_t)b * CAP;
    int cnt = gcur[b];
    if (cnt > CAP) cnt = CAP;
    int node0 = b << BSHIFT;

    if (t < BNODES) lh[t] = 0;
    __syncthreads();
    for (int i = t; i < cnt; i += 1024)
        atomicAdd(&lh[grec[base + i] & (BNODES - 1)], 1);
    __syncthreads();
    int c = 0, ex = 0;
    if (t < BNODES) {  // waves 0,1: inclusive shfl scan over 128 bins
        c = lh[t];
        int lane = t & 63;
        int v = c;
#pragma unroll
        for (int o = 1; o < 64; o <<= 1) {
            int u = __shfl_up(v, o, 64);
            if (lane >= o) v += u;
        }
        if (t == 63) wtot = v;
        ex = v - c;
    }
    __syncthreads();
    if (t >= 64 && t < BNODES) ex += wtot;
    if (t < BNODES) {
        ls[t] = ex;
        lh[t] = 0;  // cursor
        if (t == BNODES - 1) ls[BNODES] = ex + c;
    }
    __syncthreads();
    for (int i = t; i < cnt; i += 1024) {  // re-read grec (L2-hot), sort into LDS
        unsigned int r = grec[base + i];
        int nd = r & (BNODES - 1);
        int pos = ls[nd] + atomicAdd(&lh[nd], 1);
        sorted[pos] = r >> BSHIFT;
    }
    __syncthreads();

    // ---- gather: wave w handles nodes [w*8, w*8+8) of this bucket ----
    int wave = t >> 6;
    int lane = t & 63;
    int grp = lane >> 4;   // which of 4 concurrent edges
    int fq = lane & 15;    // feature quad
    float4 bb = ((const float4*)bias)[fq];
    for (int i = 0; i < 8; ++i) {
        int nd = wave * 8 + i;
        int node = node0 + nd;
        if (node >= n) break;  // uniform per wave
        int beg = ls[nd];
        int end = ls[nd + 1];
        float dn = rsqrtf((float)(end - beg) + 1.0f);  // deg+1 (self loop)
        float4 acc = {0.f, 0.f, 0.f, 0.f};
        if (grp == 0) {  // self loop term y'_self
            ushort4 h = yh[(size_t)node * 16 + fq];
            acc.x = b2f(h.x); acc.y = b2f(h.y);
            acc.z = b2f(h.z); acc.w = b2f(h.w);
        }
        for (int j = beg; j < end; j += 4) {
            int jj = j + grp;
            if (jj < end) {  // uniform within 16-lane group
                int s = (int)sorted[jj];              // ds_read, group-broadcast
                ushort4 h = yh[(size_t)s * 16 + fq];  // 128B row
                acc.x += b2f(h.x);
                acc.y += b2f(h.y);
                acc.z += b2f(h.z);
                acc.w += b2f(h.w);
            }
        }
        for (int m = 16; m < 64; m <<= 1) {  // reduce 4 edge-groups
            acc.x += __shfl_xor(acc.x, m);
            acc.y += __shfl_xor(acc.y, m);
            acc.z += __shfl_xor(acc.z, m);
            acc.w += __shfl_xor(acc.w, m);
        }
        if (lane < 16) {
            float4 o;
            o.x = acc.x * dn + bb.x;
            o.y = acc.y * dn + bb.y;
            o.z = acc.z * dn + bb.z;
            o.w = acc.w * dn + bb.w;
            out[(size_t)node * 16 + lane] = o;
        }
    }
}

extern "C" void kernel_launch(void* const* d_in, const int* in_sizes, int n_in,
                              void* d_out, int out_size, void* d_ws, size_t ws_size,
                              hipStream_t stream) {
    const float* x    = (const float*)d_in[0];
    const int*   ei   = (const int*)d_in[1];  // [2,E]: src row then dst row
    const float* W    = (const float*)d_in[2];
    const float* bias = (const float*)d_in[3];
    float* out = (float*)d_out;

    int n = in_sizes[0] / 64;
    int e = in_sizes[1] / 2;
    int nbuck = (n + BNODES - 1) / BNODES;  // 782 (<=1152 for scatter smem carve)

    // workspace (256B aligned): deg | gcur | grec | yh  (~22.9 MB)
    auto align = [](size_t v) { return (v + 255) & ~(size_t)255; };
    char* p = (char*)d_ws;
    int* deg = (int*)p;           p += align((size_t)n * 4);
    int* gcur = (int*)p;          p += align((size_t)nbuck * 4);
    unsigned int* grec = (unsigned int*)p;  p += align((size_t)nbuck * CAP * 4);
    ushort4* yh = (ushort4*)p;

    int sblocks = (e + EPB - 1) / EPB;   // 391
    int gblocks = (n + 63) / 64;         // 1563

    // one memset covers deg + gcur (contiguous, padding zeroed harmlessly)
    hipMemsetAsync(deg, 0, (size_t)((char*)(gcur + nbuck) - (char*)deg), stream);
    hist_kernel<<<(e + 255) / 256, 256, 0, stream>>>(ei + e, deg, e);
    fused_gemm_scatter_kernel<<<sblocks + gblocks, 256, 0, stream>>>(
        x, W, deg, yh, ei, gcur, grec, n, e, nbuck, sblocks);
    csr_gather_kernel<<<nbuck, 1024, 0, stream>>>(grec, gcur, yh, bias,
                                                  (float4*)out, n);
}

// Round 10
// 179.223 us; speedup vs baseline: 3.2591x; 1.3529x over previous
//
#include <hip/hip_runtime.h>

// GCN layer: out = (D^-1/2 (A+I) D^-1/2) X W^T + b
// N=100000, E=1600000, D=64.
//
// Round 10: kill the 65us global deg-histogram (round 9's top dispatch:
// 1.6M device atomics onto 400KB = ~256 atomics/line serialized, WRITE 50MB
// write-through). deg is bucket-local in grec, so a cheap per-bucket pass
// computes it with FREE LDS atomics and applies the dis pre-scale there:
//   fused gemm emits fp32 y = xW^T (no deg dependency)
//   bucket_scale: LDS hist of own grec records -> yh[node]=bf16(y*rsqrt(deg+1))
//   csr_gather: sort + gather pre-scaled rows (no per-edge dis, no shfl stage)
// Gather upgrades: 512-thread blocks (782 blocks = 6256 waves, ALL resident
// in one round vs round-9's 1.53 rounds w/ half-empty tail) + manual 2x
// unroll of the edge loop (8 row-loads in flight/wave-iter vs 4 -> attacks
// the 2.2TB/s effective-BW latency limit).
//
// Pipeline (4 dispatches, plain launches):
//   D1 memset gcur (3KB)
//   D2 fused: gemm y=xW^T fp32 || binned scatter (round-7-proven internals)
//   D3 bucket_scale: per-bucket hist + scale -> yh bf16
//   D4 csr_gather: per-bucket LDS sort + gather + bias

#define BSHIFT 7
#define BNODES 128
#define CAP 3072   // records per bucket region (mean 2046, P(overflow)~1e-90)
#define EPB 4096   // edges per scatter block -> 391 blocks
#define SMEM_BYTES 33792  // max(gemm 33792, scatter 24576+nbuck*8, nbuck<=1152)

__device__ inline unsigned short f2b_rn(float f) {
    unsigned u = __float_as_uint(f);
    unsigned r = u + 0x7FFFu + ((u >> 16) & 1u);
    return (unsigned short)(r >> 16);
}
__device__ inline float b2f(unsigned short h) {
    return __uint_as_float(((unsigned)h) << 16);
}

// --- D2: fused gemm || scatter (independent work, one dispatch) ---
__global__ __launch_bounds__(256) void fused_gemm_scatter_kernel(
    const float* __restrict__ x, const float* __restrict__ W,
    float4* __restrict__ yf,
    const int* __restrict__ ei, int* __restrict__ gcur,
    unsigned int* __restrict__ grec,
    int n, int e, int nbuck, int sblocks) {
    __shared__ __align__(16) unsigned char smem[SMEM_BYTES];
    int t = threadIdx.x;

    if ((int)blockIdx.x < sblocks) {
        // ---- binned scatter into fixed-capacity bucket regions ----
        unsigned int* lrec = (unsigned int*)smem;               // EPB*4 = 16384
        unsigned short* lbk = (unsigned short*)(smem + 16384);  // EPB*2 = 8192
        int* lh = (int*)(smem + 24576);                         // [nbuck]
        int* lbase = lh + nbuck;                                // [nbuck]
        for (int i = t; i < nbuck; i += 256) lh[i] = 0;
        __syncthreads();
        int e0 = blockIdx.x * EPB;
        int m = e - e0;
        if (m > EPB) m = EPB;
        for (int i = t; i < m; i += 256) {
            int g = e0 + i;
            int s = ei[g];
            int d = ei[e + g];
            int b = d >> BSHIFT;
            lrec[i] = ((unsigned int)s << BSHIFT) | (unsigned int)(d & (BNODES - 1));
            lbk[i] = (unsigned short)b;
            atomicAdd(&lh[b], 1);
        }
        __syncthreads();
        for (int b = t; b < nbuck; b += 256) {
            int c = lh[b];
            lbase[b] = c ? atomicAdd(&gcur[b], c) : 0;
            lh[b] = 0;  // reuse as local cursor
        }
        __syncthreads();
        for (int i = t; i < m; i += 256) {
            int b = lbk[i];
            int pos = lbase[b] + atomicAdd(&lh[b], 1);
            if (pos < CAP)
                grec[(size_t)b * CAP + pos] = lrec[i];
        }
    } else {
        // ---- gemm: y = x @ W^T, fp32 out (scaled to bf16 later in D3) ----
        float* At = (float*)smem;            // 64*68*4 = 17408, k-major stride 68
        float* Wt = (float*)(smem + 17408);  // 64*64*4 = 16384
        int m0 = ((int)blockIdx.x - sblocks) * 64;

#pragma unroll
        for (int j = 0; j < 16; ++j) {
            int idx = t + j * 256;
            int o = idx >> 6, k = idx & 63;
            Wt[k * 64 + o] = W[idx];
        }
#pragma unroll
        for (int j = 0; j < 16; ++j) {
            int idx = t + j * 256;
            int mm = idx >> 6, k = idx & 63;
            int gm = m0 + mm;
            At[k * 68 + mm] = (gm < n) ? x[(size_t)gm * 64 + k] : 0.f;
        }
        __syncthreads();

        int tx = t & 15, ty = t >> 4;
        float acc[4][4];
#pragma unroll
        for (int i = 0; i < 4; ++i)
#pragma unroll
            for (int j = 0; j < 4; ++j) acc[i][j] = 0.f;

#pragma unroll 8
        for (int k = 0; k < 64; ++k) {
            float4 a = *(const float4*)&At[k * 68 + ty * 4];
            float4 w = *(const float4*)&Wt[k * 64 + tx * 4];
            float av[4] = {a.x, a.y, a.z, a.w};
            float wv[4] = {w.x, w.y, w.z, w.w};
#pragma unroll
            for (int i = 0; i < 4; ++i)
#pragma unroll
                for (int j = 0; j < 4; ++j) acc[i][j] += av[i] * wv[j];
        }

#pragma unroll
        for (int i = 0; i < 4; ++i) {
            int gm = m0 + ty * 4 + i;
            if (gm < n) {
                float4 v;
                v.x = acc[i][0]; v.y = acc[i][1];
                v.z = acc[i][2]; v.w = acc[i][3];
                yf[(size_t)gm * 16 + tx] = v;
            }
        }
    }
}

// --- D3: per-bucket deg (LDS hist, free) + dis pre-scale -> yh bf16 ---
__global__ __launch_bounds__(256) void bucket_scale_kernel(
    const unsigned int* __restrict__ grec, const int* __restrict__ gcur,
    const float4* __restrict__ yf, ushort4* __restrict__ yh, int n) {
    __shared__ int lh[BNODES];
    int t = threadIdx.x;
    int b = blockIdx.x;
    size_t base = (size_t)b * CAP;
    int cnt = gcur[b];
    if (cnt > CAP) cnt = CAP;
    int node0 = b << BSHIFT;
    if (t < BNODES) lh[t] = 0;
    __syncthreads();
    for (int i = t; i < cnt; i += 256)
        atomicAdd(&lh[grec[base + i] & (BNODES - 1)], 1);
    __syncthreads();
#pragma unroll
    for (int j = 0; j < 8; ++j) {
        int idx = t + j * 256;   // 0..2047 = 128 nodes x 16 float4
        int nd = idx >> 4, fq = idx & 15;
        int node = node0 + nd;
        if (node < n) {
            float dn = rsqrtf((float)(lh[nd] + 1));  // +1 self loop
            float4 v = yf[(size_t)node * 16 + fq];
            ushort4 h;
            h.x = f2b_rn(v.x * dn);
            h.y = f2b_rn(v.y * dn);
            h.z = f2b_rn(v.z * dn);
            h.w = f2b_rn(v.w * dn);
            yh[(size_t)node * 16 + fq] = h;
        }
    }
}

// --- D4: per-bucket fused sort + gather (512 thr: 782 blocks all-resident) ---
__global__ __launch_bounds__(512, 4) void csr_gather_kernel(
    const unsigned int* __restrict__ grec, const int* __restrict__ gcur,
    const ushort4* __restrict__ yh, const float* __restrict__ bias,
    float4* __restrict__ out, int n) {
    __shared__ unsigned int sorted[CAP];  // 12288 B: src ids grouped by dst
    __shared__ int lh[BNODES];            // hist, then cursor
    __shared__ int ls[BNODES + 1];        // exclusive offsets; ls[128] = cnt
    __shared__ int wtot;
    int t = threadIdx.x;
    int b = blockIdx.x;
    size_t base = (size_t)b * CAP;
    int cnt = gcur[b];
    if (cnt > CAP) cnt = CAP;
    int node0 = b << BSHIFT;

    if (t < BNODES) lh[t] = 0;
    __syncthreads();
    for (int i = t; i < cnt; i += 512)
        atomicAdd(&lh[grec[base + i] & (BNODES - 1)], 1);
    __syncthreads();
    int c = 0, ex = 0;
    if (t < BNODES) {  // waves 0,1: inclusive shfl scan over 128 bins
        c = lh[t];
        int lane64 = t & 63;
        int v = c;
#pragma unroll
        for (int o = 1; o < 64; o <<= 1) {
            int u = __shfl_up(v, o, 64);
            if (lane64 >= o) v += u;
        }
        if (t == 63) wtot = v;
        ex = v - c;
    }
    __syncthreads();
    if (t >= 64 && t < BNODES) ex += wtot;
    if (t < BNODES) {
        ls[t] = ex;
        lh[t] = 0;  // cursor
        if (t == BNODES - 1) ls[BNODES] = ex + c;
    }
    __syncthreads();
    for (int i = t; i < cnt; i += 512) {  // re-read grec (L2-hot), sort into LDS
        unsigned int r = grec[base + i];
        int nd = r & (BNODES - 1);
        int pos = ls[nd] + atomicAdd(&lh[nd], 1);
        sorted[pos] = r >> BSHIFT;
    }
    __syncthreads();

    // ---- gather: wave w handles nodes [w*16, w*16+16) of this bucket ----
    int wave = t >> 6;
    int lane = t & 63;
    int grp = lane >> 4;   // which of 4 concurrent edges
    int fq = lane & 15;    // feature quad
    float4 bb = ((const float4*)bias)[fq];
    for (int i = 0; i < 16; ++i) {
        int nd = wave * 16 + i;
        int node = node0 + nd;
        if (node >= n) break;  // uniform per wave
        int beg = ls[nd];
        int end = ls[nd + 1];
        float dn = rsqrtf((float)(end - beg) + 1.0f);  // deg+1 (self loop)
        float4 acc = {0.f, 0.f, 0.f, 0.f};
        if (grp == 0) {  // self loop term y'_self
            ushort4 h = yh[(size_t)node * 16 + fq];
            acc.x = b2f(h.x); acc.y = b2f(h.y);
            acc.z = b2f(h.z); acc.w = b2f(h.w);
        }
        int j = beg + grp;
        // 2x unrolled: two independent row loads in flight per iteration
        for (; j + 4 < end; j += 8) {
            int s0 = (int)sorted[j];
            int s1 = (int)sorted[j + 4];
            ushort4 h0 = yh[(size_t)s0 * 16 + fq];  // 128B row
            ushort4 h1 = yh[(size_t)s1 * 16 + fq];
            acc.x += b2f(h0.x) + b2f(h1.x);
            acc.y += b2f(h0.y) + b2f(h1.y);
            acc.z += b2f(h0.z) + b2f(h1.z);
            acc.w += b2f(h0.w) + b2f(h1.w);
        }
        if (j < end) {  // at most one tail element per group (stride 4)
            int s = (int)sorted[j];
            ushort4 h = yh[(size_t)s * 16 + fq];
            acc.x += b2f(h.x); acc.y += b2f(h.y);
            acc.z += b2f(h.z); acc.w += b2f(h.w);
        }
        for (int m = 16; m < 64; m <<= 1) {  // reduce 4 edge-groups
            acc.x += __shfl_xor(acc.x, m);
            acc.y += __shfl_xor(acc.y, m);
            acc.z += __shfl_xor(acc.z, m);
            acc.w += __shfl_xor(acc.w, m);
        }
        if (lane < 16) {
            float4 o;
            o.x = acc.x * dn + bb.x;
            o.y = acc.y * dn + bb.y;
            o.z = acc.z * dn + bb.z;
            o.w = acc.w * dn + bb.w;
            out[(size_t)node * 16 + lane] = o;
        }
    }
}

extern "C" void kernel_launch(void* const* d_in, const int* in_sizes, int n_in,
                              void* d_out, int out_size, void* d_ws, size_t ws_size,
                              hipStream_t stream) {
    const float* x    = (const float*)d_in[0];
    const int*   ei   = (const int*)d_in[1];  // [2,E]: src row then dst row
    const float* W    = (const float*)d_in[2];
    const float* bias = (const float*)d_in[3];
    float* out = (float*)d_out;

    int n = in_sizes[0] / 64;
    int e = in_sizes[1] / 2;
    int nbuck = (n + BNODES - 1) / BNODES;  // 782 (<=1152 for scatter smem carve)

    // workspace (256B aligned): gcur | grec | yf | yh  (~48 MB)
    auto align = [](size_t v) { return (v + 255) & ~(size_t)255; };
    char* p = (char*)d_ws;
    int* gcur = (int*)p;          p += align((size_t)nbuck * 4);
    unsigned int* grec = (unsigned int*)p;  p += align((size_t)nbuck * CAP * 4);
    float4* yf = (float4*)p;      p += align((size_t)n * 64 * 4);
    ushort4* yh = (ushort4*)p;

    int sblocks = (e + EPB - 1) / EPB;   // 391
    int gblocks = (n + 63) / 64;         // 1563

    hipMemsetAsync(gcur, 0, (size_t)nbuck * 4, stream);
    fused_gemm_scatter_kernel<<<sblocks + gblocks, 256, 0, stream>>>(
        x, W, yf, ei, gcur, grec, n, e, nbuck, sblocks);
    bucket_scale_kernel<<<nbuck, 256, 0, stream>>>(grec, gcur, yf, yh, n);
    csr_gather_kernel<<<nbuck, 512, 0, stream>>>(grec, gcur, yh, bias,
                                                 (float4*)out, n);
}

// Round 11
// 170.752 us; speedup vs baseline: 3.4208x; 1.0496x over previous
//
#include <hip/hip_runtime.h>

// GCN layer: out = (D^-1/2 (A+I) D^-1/2) X W^T + b
// N=100000, E=1600000, D=64.
//
// Round 11: kill the 7.18M LDS bank conflicts in the fused kernel's gemm
// staging (round-10 counter, deterministic): Wt[k*64+o] scalar writes put
// all 64 lanes of a wave on ONE bank (stride 64 floats = bank const/wave,
// ~6.2M cycles); At stride-68 writes were 8-way (~0.6M). Fix: float4
// staging with XOR swizzle — T4[k*16 + (r ^ (k&15))] = {T[4r..4r+3][k]}:
//   write: 16 distinct quad-slots per wave -> <=2 lanes/bank (free, m136)
//   read:  k uniform per iter -> 4-16 distinct addrs -> broadcast, free
//   global staging reads stay lane-consecutive-k coalesced
// Plus: csr_gather edge loop 4x unroll (16 outstanding 128B loads/wave,
// was 8) — the gather is latency-bound, MLP is the lever.
//
// Pipeline (4 dispatches):
//   D1 memset gcur (3KB)
//   D2 fused: gemm y=xW^T fp32 || binned scatter
//   D3 bucket_scale: per-bucket LDS hist (free) -> yh = bf16(y*rsqrt(deg+1))
//   D4 csr_gather: per-bucket LDS sort + gather pre-scaled rows + bias

#define BSHIFT 7
#define BNODES 128
#define CAP 3072   // records per bucket region (mean 2046, P(overflow)~1e-90)
#define EPB 4096   // edges per scatter block -> 391 blocks
#define SMEM_BYTES 32768  // max(gemm 32768, scatter 24576+nbuck*8<=30832)

__device__ inline unsigned short f2b_rn(float f) {
    unsigned u = __float_as_uint(f);
    unsigned r = u + 0x7FFFu + ((u >> 16) & 1u);
    return (unsigned short)(r >> 16);
}
__device__ inline float b2f(unsigned short h) {
    return __uint_as_float(((unsigned)h) << 16);
}

// --- D2: fused gemm || scatter (independent work, one dispatch) ---
__global__ __launch_bounds__(256) void fused_gemm_scatter_kernel(
    const float* __restrict__ x, const float* __restrict__ W,
    float4* __restrict__ yf,
    const int* __restrict__ ei, int* __restrict__ gcur,
    unsigned int* __restrict__ grec,
    int n, int e, int nbuck, int sblocks) {
    __shared__ __align__(16) unsigned char smem[SMEM_BYTES];
    int t = threadIdx.x;

    if ((int)blockIdx.x < sblocks) {
        // ---- binned scatter into fixed-capacity bucket regions ----
        unsigned int* lrec = (unsigned int*)smem;               // EPB*4 = 16384
        unsigned short* lbk = (unsigned short*)(smem + 16384);  // EPB*2 = 8192
        int* lh = (int*)(smem + 24576);                         // [nbuck]
        int* lbase = lh + nbuck;                                // [nbuck]
        for (int i = t; i < nbuck; i += 256) lh[i] = 0;
        __syncthreads();
        int e0 = blockIdx.x * EPB;
        int m = e - e0;
        if (m > EPB) m = EPB;
        for (int i = t; i < m; i += 256) {
            int g = e0 + i;
            int s = ei[g];
            int d = ei[e + g];
            int b = d >> BSHIFT;
            lrec[i] = ((unsigned int)s << BSHIFT) | (unsigned int)(d & (BNODES - 1));
            lbk[i] = (unsigned short)b;
            atomicAdd(&lh[b], 1);
        }
        __syncthreads();
        for (int b = t; b < nbuck; b += 256) {
            int c = lh[b];
            lbase[b] = c ? atomicAdd(&gcur[b], c) : 0;
            lh[b] = 0;  // reuse as local cursor
        }
        __syncthreads();
        for (int i = t; i < m; i += 256) {
            int b = lbk[i];
            int pos = lbase[b] + atomicAdd(&lh[b], 1);
            if (pos < CAP)
                grec[(size_t)b * CAP + pos] = lrec[i];
        }
    } else {
        // ---- gemm: y = x @ W^T, fp32 out; XOR-swizzled float4 LDS tiles ----
        float4* At4 = (float4*)smem;             // [64*16] At4[k*16 + (r^(k&15))] = A[4r..+3][k]
        float4* Wt4 = (float4*)(smem + 16384);   // [64*16] same layout for W
        int m0 = ((int)blockIdx.x - sblocks) * 64;

#pragma unroll
        for (int j = 0; j < 4; ++j) {
            int idx = t + j * 256;      // 0..1023
            int k = idx & 63;           // lane-consecutive -> coalesced global
            int r = idx >> 6;           // quad row index 0..15
            // W tile: rows 4r..4r+3 at col k
            float4 wv;
            wv.x = W[(size_t)(4 * r + 0) * 64 + k];
            wv.y = W[(size_t)(4 * r + 1) * 64 + k];
            wv.z = W[(size_t)(4 * r + 2) * 64 + k];
            wv.w = W[(size_t)(4 * r + 3) * 64 + k];
            Wt4[k * 16 + (r ^ (k & 15))] = wv;
            // A tile: rows m0+4r..+3 at col k (guarded)
            float4 av;
            int gm = m0 + 4 * r;
            av.x = (gm + 0 < n) ? x[(size_t)(gm + 0) * 64 + k] : 0.f;
            av.y = (gm + 1 < n) ? x[(size_t)(gm + 1) * 64 + k] : 0.f;
            av.z = (gm + 2 < n) ? x[(size_t)(gm + 2) * 64 + k] : 0.f;
            av.w = (gm + 3 < n) ? x[(size_t)(gm + 3) * 64 + k] : 0.f;
            At4[k * 16 + (r ^ (k & 15))] = av;
        }
        __syncthreads();

        int tx = t & 15, ty = t >> 4;  // tx: out quad, ty: row quad
        float acc[4][4];
#pragma unroll
        for (int i = 0; i < 4; ++i)
#pragma unroll
            for (int j = 0; j < 4; ++j) acc[i][j] = 0.f;

#pragma unroll 8
        for (int k = 0; k < 64; ++k) {
            float4 a = At4[k * 16 + (ty ^ (k & 15))];  // rows ty*4..+3 @ k (broadcast)
            float4 w = Wt4[k * 16 + (tx ^ (k & 15))];  // cols tx*4..+3 @ k
            float av[4] = {a.x, a.y, a.z, a.w};
            float wv[4] = {w.x, w.y, w.z, w.w};
#pragma unroll
            for (int i = 0; i < 4; ++i)
#pragma unroll
                for (int j = 0; j < 4; ++j) acc[i][j] += av[i] * wv[j];
        }

#pragma unroll
        for (int i = 0; i < 4; ++i) {
            int gm = m0 + ty * 4 + i;
            if (gm < n) {
                float4 v;
                v.x = acc[i][0]; v.y = acc[i][1];
                v.z = acc[i][2]; v.w = acc[i][3];
                yf[(size_t)gm * 16 + tx] = v;
            }
        }
    }
}

// --- D3: per-bucket deg (LDS hist, free) + dis pre-scale -> yh bf16 ---
__global__ __launch_bounds__(256) void bucket_scale_kernel(
    const unsigned int* __restrict__ grec, const int* __restrict__ gcur,
    const float4* __restrict__ yf, ushort4* __restrict__ yh, int n) {
    __shared__ int lh[BNODES];
    int t = threadIdx.x;
    int b = blockIdx.x;
    size_t base = (size_t)b * CAP;
    int cnt = gcur[b];
    if (cnt > CAP) cnt = CAP;
    int node0 = b << BSHIFT;
    if (t < BNODES) lh[t] = 0;
    __syncthreads();
    for (int i = t; i < cnt; i += 256)
        atomicAdd(&lh[grec[base + i] & (BNODES - 1)], 1);
    __syncthreads();
#pragma unroll
    for (int j = 0; j < 8; ++j) {
        int idx = t + j * 256;   // 0..2047 = 128 nodes x 16 float4
        int nd = idx >> 4, fq = idx & 15;
        int node = node0 + nd;
        if (node < n) {
            float dn = rsqrtf((float)(lh[nd] + 1));  // +1 self loop
            float4 v = yf[(size_t)node * 16 + fq];
            ushort4 h;
            h.x = f2b_rn(v.x * dn);
            h.y = f2b_rn(v.y * dn);
            h.z = f2b_rn(v.z * dn);
            h.w = f2b_rn(v.w * dn);
            yh[(size_t)node * 16 + fq] = h;
        }
    }
}

// --- D4: per-bucket fused sort + gather (512 thr: 782 blocks all-resident) ---
__global__ __launch_bounds__(512, 4) void csr_gather_kernel(
    const unsigned int* __restrict__ grec, const int* __restrict__ gcur,
    const ushort4* __restrict__ yh, const float* __restrict__ bias,
    float4* __restrict__ out, int n) {
    __shared__ unsigned int sorted[CAP];  // 12288 B: src ids grouped by dst
    __shared__ int lh[BNODES];            // hist, then cursor
    __shared__ int ls[BNODES + 1];        // exclusive offsets; ls[128] = cnt
    __shared__ int wtot;
    int t = threadIdx.x;
    int b = blockIdx.x;
    size_t base = (size_t)b * CAP;
    int cnt = gcur[b];
    if (cnt > CAP) cnt = CAP;
    int node0 = b << BSHIFT;

    if (t < BNODES) lh[t] = 0;
    __syncthreads();
    for (int i = t; i < cnt; i += 512)
        atomicAdd(&lh[grec[base + i] & (BNODES - 1)], 1);
    __syncthreads();
    int c = 0, ex = 0;
    if (t < BNODES) {  // waves 0,1: inclusive shfl scan over 128 bins
        c = lh[t];
        int lane64 = t & 63;
        int v = c;
#pragma unroll
        for (int o = 1; o < 64; o <<= 1) {
            int u = __shfl_up(v, o, 64);
            if (lane64 >= o) v += u;
        }
        if (t == 63) wtot = v;
        ex = v - c;
    }
    __syncthreads();
    if (t >= 64 && t < BNODES) ex += wtot;
    if (t < BNODES) {
        ls[t] = ex;
        lh[t] = 0;  // cursor
        if (t == BNODES - 1) ls[BNODES] = ex + c;
    }
    __syncthreads();
    for (int i = t; i < cnt; i += 512) {  // re-read grec (L2-hot), sort into LDS
        unsigned int r = grec[base + i];
        int nd = r & (BNODES - 1);
        int pos = ls[nd] + atomicAdd(&lh[nd], 1);
        sorted[pos] = r >> BSHIFT;
    }
    __syncthreads();

    // ---- gather: wave w handles nodes [w*16, w*16+16) of this bucket ----
    int wave = t >> 6;
    int lane = t & 63;
    int grp = lane >> 4;   // which of 4 concurrent edges
    int fq = lane & 15;    // feature quad
    float4 bb = ((const float4*)bias)[fq];
    for (int i = 0; i < 16; ++i) {
        int nd = wave * 16 + i;
        int node = node0 + nd;
        if (node >= n) break;  // uniform per wave
        int beg = ls[nd];
        int end = ls[nd + 1];
        float dn = rsqrtf((float)(end - beg) + 1.0f);  // deg+1 (self loop)
        float4 acc = {0.f, 0.f, 0.f, 0.f};
        if (grp == 0) {  // self loop term y'_self
            ushort4 h = yh[(size_t)node * 16 + fq];
            acc.x = b2f(h.x); acc.y = b2f(h.y);
            acc.z = b2f(h.z); acc.w = b2f(h.w);
        }
        int j = beg + grp;
        // 4x unrolled: four independent row loads in flight per iteration
        for (; j + 12 < end; j += 16) {
            int s0 = (int)sorted[j];
            int s1 = (int)sorted[j + 4];
            int s2 = (int)sorted[j + 8];
            int s3 = (int)sorted[j + 12];
            ushort4 h0 = yh[(size_t)s0 * 16 + fq];  // 128B rows
            ushort4 h1 = yh[(size_t)s1 * 16 + fq];
            ushort4 h2 = yh[(size_t)s2 * 16 + fq];
            ushort4 h3 = yh[(size_t)s3 * 16 + fq];
            acc.x += b2f(h0.x) + b2f(h1.x) + b2f(h2.x) + b2f(h3.x);
            acc.y += b2f(h0.y) + b2f(h1.y) + b2f(h2.y) + b2f(h3.y);
            acc.z += b2f(h0.z) + b2f(h1.z) + b2f(h2.z) + b2f(h3.z);
            acc.w += b2f(h0.w) + b2f(h1.w) + b2f(h2.w) + b2f(h3.w);
        }
        for (; j < end; j += 4) {  // tail, one per group-stride
            int s = (int)sorted[j];
            ushort4 h = yh[(size_t)s * 16 + fq];
            acc.x += b2f(h.x); acc.y += b2f(h.y);
            acc.z += b2f(h.z); acc.w += b2f(h.w);
        }
        for (int m = 16; m < 64; m <<= 1) {  // reduce 4 edge-groups
            acc.x += __shfl_xor(acc.x, m);
            acc.y += __shfl_xor(acc.y, m);
            acc.z += __shfl_xor(acc.z, m);
            acc.w += __shfl_xor(acc.w, m);
        }
        if (lane < 16) {
            float4 o;
            o.x = acc.x * dn + bb.x;
            o.y = acc.y * dn + bb.y;
            o.z = acc.z * dn + bb.z;
            o.w = acc.w * dn + bb.w;
            out[(size_t)node * 16 + lane] = o;
        }
    }
}

extern "C" void kernel_launch(void* const* d_in, const int* in_sizes, int n_in,
                              void* d_out, int out_size, void* d_ws, size_t ws_size,
                              hipStream_t stream) {
    const float* x    = (const float*)d_in[0];
    const int*   ei   = (const int*)d_in[1];  // [2,E]: src row then dst row
    const float* W    = (const float*)d_in[2];
    const float* bias = (const float*)d_in[3];
    float* out = (float*)d_out;

    int n = in_sizes[0] / 64;
    int e = in_sizes[1] / 2;
    int nbuck = (n + BNODES - 1) / BNODES;  // 782 (<=1024 for scatter smem carve)

    // workspace (256B aligned): gcur | grec | yf | yh  (~48 MB)
    auto align = [](size_t v) { return (v + 255) & ~(size_t)255; };
    char* p = (char*)d_ws;
    int* gcur = (int*)p;          p += align((size_t)nbuck * 4);
    unsigned int* grec = (unsigned int*)p;  p += align((size_t)nbuck * CAP * 4);
    float4* yf = (float4*)p;      p += align((size_t)n * 64 * 4);
    ushort4* yh = (ushort4*)p;

    int sblocks = (e + EPB - 1) / EPB;   // 391
    int gblocks = (n + 63) / 64;         // 1563

    hipMemsetAsync(gcur, 0, (size_t)nbuck * 4, stream);
    fused_gemm_scatter_kernel<<<sblocks + gblocks, 256, 0, stream>>>(
        x, W, yf, ei, gcur, grec, n, e, nbuck, sblocks);
    bucket_scale_kernel<<<nbuck, 256, 0, stream>>>(grec, gcur, yf, yh, n);
    csr_gather_kernel<<<nbuck, 512, 0, stream>>>(grec, gcur, yh, bias,
                                                 (float4*)out, n);
}